// Round 1
// baseline (431.036 us; speedup 1.0000x reference)
//
#include <hip/hip_runtime.h>
#include <math.h>

#define F_IN 10000
#define NROWS 4096
#define NPADCOL 10240          // padded to 40 chunks of 256 cols
#define NQ 2560                // 4-col groups (NPADCOL/4)
#define CGROUPS 8
#define ROWS_PER_WAVE 4        // 4 rows/wave x 4 waves = 16 rows/block

#define LOG2E      1.44269504088896340736f
#define SQRT_LOG2E 1.20112240878645f   // sqrt(log2(e))
#define LN2        0.69314718055994530942f

// ws layout (AoS by 4-col group q): ws[q*36 + t], t = A0[4] A1[4] A2[4] B0[4] B1[4] B2[4] C0[4] C1[4] C2[4]
// log2-domain: v_m = c_m - (a_m*x + b_m)^2 equals log2-prob (a,b carry sqrt(log2e), c carries log2e)
__global__ void spn_prep_kernel(const float* __restrict__ means,
                                const float* __restrict__ stds,
                                const float* __restrict__ w1,
                                const int* __restrict__ rand_idxs,
                                float* __restrict__ ws,
                                float* __restrict__ out) {
    int f = blockIdx.x * blockDim.x + threadIdx.x;   // 0..10239 (40 blocks x 256)
    if (f < NROWS) out[f] = 0.0f;                    // zero output for atomic accumulation
    if (f >= NPADCOL) return;

    if (f >= F_IN) {
        // pad columns: neutral params -> v0=0, v1=v2=-1e30 => mx=0, s=1 (no contribution)
        int q = f >> 2, sl = f & 3;
        float* base = ws + q * 36;
#pragma unroll
        for (int m = 0; m < 3; m++) {
            base[m * 4 + sl]      = 0.0f;                       // A
            base[12 + m * 4 + sl] = 0.0f;                       // B
            base[24 + m * 4 + sl] = (m == 0) ? 0.0f : -1e30f;   // C
        }
        return;
    }

    int j = rand_idxs[f];                   // column of x this feature reads
    int q = j >> 2, sl = j & 3;
    float* base = ws + q * 36;

    float wa = w1[f * 3 + 0];
    float wb = w1[f * 3 + 1];
    float wc = w1[f * 3 + 2];
    float wm = fmaxf(fmaxf(wa, wb), wc);
    float lse = wm + __logf(__expf(wa - wm) + __expf(wb - wm) + __expf(wc - wm));

    const float INV_SQRT2 = 0.70710678118654752440f;
    const float HALF_LOG_2PI = 0.91893853320467274178f;

#pragma unroll
    for (int m = 0; m < 3; m++) {
        float w  = w1[f * 3 + m] - lse;                 // log_softmax (natural log)
        float sd = stds[f * 3 + m];
        float mu = means[f * 3 + m];
        float a  = (INV_SQRT2 * SQRT_LOG2E) / sd;       // sqrt(log2e) folded in
        float b  = -mu * a;
        float c  = (w - __logf(sd) - HALF_LOG_2PI) * LOG2E;
        base[m * 4 + sl]      = a;
        base[12 + m * 4 + sl] = b;
        base[24 + m * 4 + sl] = c;
    }
}

// per-column mixture term in log2 domain: mx = max of 3 log2-probs, s = sum 2^(v-mx), s in [1,3]
__device__ __forceinline__ void col_term(float xv,
                                         float a0, float b0, float c0,
                                         float a1, float b1, float c1,
                                         float a2, float b2, float c2,
                                         float& mx_out, float& s_out) {
    float u0 = fmaf(xv, a0, b0);
    float u1 = fmaf(xv, a1, b1);
    float u2 = fmaf(xv, a2, b2);
    float v0 = fmaf(-u0, u0, c0);           // c - (z^2/2)*log2e
    float v1 = fmaf(-u1, u1, c1);
    float v2 = fmaf(-u2, u2, c2);
    float mx = fmaxf(fmaxf(v0, v1), v2);    // -> v_max3
    float me = __builtin_amdgcn_fmed3f(v0, v1, v2);
    float mn = fminf(fminf(v0, v1), v2);    // -> v_min3
    float s  = 1.0f + exp2f(me - mx) + exp2f(mn - mx);   // exp2f = native v_exp_f32, no x1.4427 mul
    mx_out = mx;
    s_out  = s;
}

// 256 row-blocks (16 rows) x 8 column-groups = 2048 blocks; 4 waves/block
// launch_bounds(256,4): force VGPR<=128 -> 4 waves/SIMD, 16 waves/CU
__global__ __launch_bounds__(256, 4) void spn_main_kernel(const float* __restrict__ x,
                                                          const float* __restrict__ ws,
                                                          float* __restrict__ out) {
    const int wave = threadIdx.x >> 6;
    const int lane = threadIdx.x & 63;
    const int rb   = blockIdx.x >> 3;       // row-block: 0..255
    const int cg   = blockIdx.x & 7;        // column-group: 0..7
    const int row0 = rb * (ROWS_PER_WAVE * 4) + wave * ROWS_PER_WAVE;

    float accm[ROWS_PER_WAVE];              // sum of per-col maxes (log2 domain)
    float prod[ROWS_PER_WAVE];              // product of s factors (<= 3^20, safe in fp32)
#pragma unroll
    for (int r = 0; r < ROWS_PER_WAVE; r++) { accm[r] = 0.0f; prod[r] = 1.0f; }

    // per-lane AoS param pointer: q0 = cg*64 + lane; 9 float4 per q; q advances 512 per it
    const float4* wp = (const float4*)(ws + (size_t)(cg * 64 + lane) * 36);

    const int jc0 = cg * 256 + lane * 4;
    int xoff[ROWS_PER_WAVE];                // 32-bit element offsets (max ~41M, fits int)
#pragma unroll
    for (int r = 0; r < ROWS_PER_WAVE; r++) xoff[r] = (row0 + r) * F_IN;

    // prologue: it0 x loads (chunk cg, always fully valid)
    float4 xv[ROWS_PER_WAVE];
#pragma unroll
    for (int r = 0; r < ROWS_PER_WAVE; r++)
        xv[r] = *(const float4*)(x + xoff[r] + jc0);

#pragma unroll
    for (int it = 0; it < 5; ++it) {
        // current chunk params FIRST (L2-hot, ~200cy): 9 contiguous float4, imm offsets 0..128B.
        // Issue order matters: ws before x-prefetch so vmcnt-wait for A0 does NOT drain the HBM loads.
        const float4 A0 = wp[0], A1 = wp[1], A2 = wp[2];
        const float4 B0 = wp[3], B1 = wp[4], B2 = wp[5];
        const float4 C0 = wp[6], C1 = wp[7], C2 = wp[8];
        wp += 512 * 9;

        // software-pipeline: issue next chunk's x loads (HBM) before computing
        float4 xn[ROWS_PER_WAVE];
        if (it < 4) {
            int jn = jc0 + (it + 1) * 2048;
            jn = (jn < F_IN) ? jn : 0;      // pad cols: loaded value irrelevant (a=0), only address safety
#pragma unroll
            for (int r = 0; r < ROWS_PER_WAVE; r++)
                xn[r] = *(const float4*)(x + xoff[r] + jn);
        }

#pragma unroll
        for (int r = 0; r < ROWS_PER_WAVE; r++) {
            float m0, s0, m1, s1, m2, s2, m3, s3;
            col_term(xv[r].x, A0.x, B0.x, C0.x, A1.x, B1.x, C1.x, A2.x, B2.x, C2.x, m0, s0);
            col_term(xv[r].y, A0.y, B0.y, C0.y, A1.y, B1.y, C1.y, A2.y, B2.y, C2.y, m1, s1);
            col_term(xv[r].z, A0.z, B0.z, C0.z, A1.z, B1.z, C1.z, A2.z, B2.z, C2.z, m2, s2);
            col_term(xv[r].w, A0.w, B0.w, C0.w, A1.w, B1.w, C1.w, A2.w, B2.w, C2.w, m3, s3);
            // no masking: pad columns contribute mx=0, s=1 by construction
            accm[r] += (m0 + m1) + (m2 + m3);
            prod[r] *= (s0 * s1) * (s2 * s3);
        }

        if (it < 4) {
#pragma unroll
            for (int r = 0; r < ROWS_PER_WAVE; r++) xv[r] = xn[r];
        }
    }

#pragma unroll
    for (int r = 0; r < ROWS_PER_WAVE; r++) {
        float part = LN2 * (accm[r] + __log2f(prod[r]));   // back to natural-log domain
#pragma unroll
        for (int off = 32; off > 0; off >>= 1)
            part += __shfl_xor(part, off, 64);
        if (lane == 0)
            atomicAdd(&out[row0 + r], part);
    }
}

extern "C" void kernel_launch(void* const* d_in, const int* in_sizes, int n_in,
                              void* d_out, int out_size, void* d_ws, size_t ws_size,
                              hipStream_t stream) {
    const float* x         = (const float*)d_in[0];
    const float* means     = (const float*)d_in[1];
    const float* stds      = (const float*)d_in[2];
    const float* w1        = (const float*)d_in[3];
    // w2..w5 (d_in[4..7]) are identity under log_softmax over a size-1 axis
    const int*   rand_idxs = (const int*)d_in[8];

    float* out = (float*)d_out;
    float* ws  = (float*)d_ws;   // needs NQ * 36 * 4 B = 368,640 B

    // prep: AoS log2-domain constants (incl. neutral pad cols) + zero the output
    spn_prep_kernel<<<NPADCOL / 256, 256, 0, stream>>>(means, stds, w1, rand_idxs, ws, out);

    // main: 256 row-blocks (16 rows) x 8 column-groups = 2048 blocks
    spn_main_kernel<<<256 * CGROUPS, 256, 0, stream>>>(x, ws, out);
}

// Round 2
// 265.398 us; speedup vs baseline: 1.6241x; 1.6241x over previous
//
#include <hip/hip_runtime.h>
#include <math.h>

#define F_IN 10000
#define NROWS 4096
#define NPADCOL 10240          // padded to 40 chunks of 256 cols
#define CGROUPS 8
#define ROWS_PER_WAVE 4        // 4 rows/wave x 4 waves = 16 rows/block

#define LOG2E      1.44269504088896340736f
#define SQRT_LOG2E 1.20112240878645f   // sqrt(log2(e))
#define LN2        0.69314718055994530942f

// ws layout: SoA, 9 arrays of NPADCOL floats, column-ordered (coalesced across lanes):
//   [0..2]*NPADCOL : A_m = sqrt(log2e)/(std*sqrt(2))
//   [3..5]*NPADCOL : B_m = -mean*A_m
//   [6..8]*NPADCOL : C_m = (logw_m - log(std) - 0.5*log(2pi)) * log2e
// log2-domain: v_m = C_m - (A_m*x + B_m)^2 is the log2-prob of component m.
// Pad columns j in [10000,10240): A=B=0, C=(0,-1e30,-1e30) -> mx=0, s=1 (neutral).
__global__ void spn_prep_kernel(const float* __restrict__ means,
                                const float* __restrict__ stds,
                                const float* __restrict__ w1,
                                const int* __restrict__ rand_idxs,
                                float* __restrict__ ws,
                                float* __restrict__ out) {
    int f = blockIdx.x * blockDim.x + threadIdx.x;   // 0..10239 (40 blocks x 256)
    if (f < NROWS) out[f] = 0.0f;                    // zero output for atomic accumulation
    if (f >= NPADCOL) return;

    if (f >= F_IN) {
        // rand_idxs is a permutation of 0..9999, so columns >=10000 are exactly the pads
#pragma unroll
        for (int m = 0; m < 3; m++) {
            ws[(0 + m) * NPADCOL + f] = 0.0f;                       // A
            ws[(3 + m) * NPADCOL + f] = 0.0f;                       // B
            ws[(6 + m) * NPADCOL + f] = (m == 0) ? 0.0f : -1e30f;   // C
        }
        return;
    }

    int j = rand_idxs[f];                   // column of x this feature reads

    float wa = w1[f * 3 + 0];
    float wb = w1[f * 3 + 1];
    float wc = w1[f * 3 + 2];
    float wm = fmaxf(fmaxf(wa, wb), wc);
    float lse = wm + __logf(__expf(wa - wm) + __expf(wb - wm) + __expf(wc - wm));

    const float INV_SQRT2 = 0.70710678118654752440f;
    const float HALF_LOG_2PI = 0.91893853320467274178f;

#pragma unroll
    for (int m = 0; m < 3; m++) {
        float w  = w1[f * 3 + m] - lse;                 // log_softmax (natural log)
        float sd = stds[f * 3 + m];
        float mu = means[f * 3 + m];
        float a  = (INV_SQRT2 * SQRT_LOG2E) / sd;       // sqrt(log2e) folded into scale
        float b  = -mu * a;
        float c  = (w - __logf(sd) - HALF_LOG_2PI) * LOG2E;
        ws[(0 + m) * NPADCOL + j] = a;
        ws[(3 + m) * NPADCOL + j] = b;
        ws[(6 + m) * NPADCOL + j] = c;
    }
}

// per-column mixture term in log2 domain: mx = max of 3 log2-probs, s = sum 2^(v-mx), s in [1,3]
__device__ __forceinline__ void col_term(float xv,
                                         float a0, float b0, float c0,
                                         float a1, float b1, float c1,
                                         float a2, float b2, float c2,
                                         float& mx_out, float& s_out) {
    float u0 = fmaf(xv, a0, b0);
    float u1 = fmaf(xv, a1, b1);
    float u2 = fmaf(xv, a2, b2);
    float v0 = fmaf(-u0, u0, c0);           // C - (z^2/2)*log2e
    float v1 = fmaf(-u1, u1, c1);
    float v2 = fmaf(-u2, u2, c2);
    float mx = fmaxf(fmaxf(v0, v1), v2);    // -> v_max3
    float me = __builtin_amdgcn_fmed3f(v0, v1, v2);
    float mn = fminf(fminf(v0, v1), v2);    // -> v_min3
    float s  = 1.0f + exp2f(me - mx) + exp2f(mn - mx);   // native v_exp_f32, no 1.4427 muls
    mx_out = mx;
    s_out  = s;
}

// 256 row-blocks (16 rows) x 8 column-groups = 2048 blocks; 4 waves/block; 8 blocks/CU
__global__ __launch_bounds__(256) void spn_main_kernel(const float* __restrict__ x,
                                                       const float* __restrict__ ws,
                                                       float* __restrict__ out) {
    const int wave = threadIdx.x >> 6;
    const int lane = threadIdx.x & 63;
    const int rb   = blockIdx.x >> 3;       // row-block: 0..255
    const int cg   = blockIdx.x & 7;        // column-group: 0..7
    const int row0 = rb * (ROWS_PER_WAVE * 4) + wave * ROWS_PER_WAVE;

    float accm[ROWS_PER_WAVE];              // sum of per-col maxes (log2 domain)
    float prod[ROWS_PER_WAVE];              // product of s factors (<= 3^20, safe in fp32)
#pragma unroll
    for (int r = 0; r < ROWS_PER_WAVE; r++) { accm[r] = 0.0f; prod[r] = 1.0f; }

    const float* xr[ROWS_PER_WAVE];
#pragma unroll
    for (int r = 0; r < ROWS_PER_WAVE; r++) xr[r] = x + (size_t)(row0 + r) * F_IN;

    // prologue: it0 x loads (chunk cg, always fully valid since cg < 8)
    float4 xv[ROWS_PER_WAVE];
    {
        int jc = cg * 256 + lane * 4;
#pragma unroll
        for (int r = 0; r < ROWS_PER_WAVE; r++)
            xv[r] = *(const float4*)(xr[r] + jc);
    }

#pragma unroll
    for (int it = 0; it < 5; ++it) {
        const int c = cg + it * 8;
        const int q = (c * 256 + lane * 4) >> 2;   // always < 2560 (padded arrays)

        // current chunk params (SoA, coalesced: lanes read consecutive float4s; L2-hot)
        const float4 A0 = ((const float4*)(ws + 0 * NPADCOL))[q];
        const float4 A1 = ((const float4*)(ws + 1 * NPADCOL))[q];
        const float4 A2 = ((const float4*)(ws + 2 * NPADCOL))[q];
        const float4 B0 = ((const float4*)(ws + 3 * NPADCOL))[q];
        const float4 B1 = ((const float4*)(ws + 4 * NPADCOL))[q];
        const float4 B2 = ((const float4*)(ws + 5 * NPADCOL))[q];
        const float4 C0 = ((const float4*)(ws + 6 * NPADCOL))[q];
        const float4 C1 = ((const float4*)(ws + 7 * NPADCOL))[q];
        const float4 C2 = ((const float4*)(ws + 8 * NPADCOL))[q];

        // software-pipeline: issue next chunk's x loads (HBM) before computing
        float4 xn[ROWS_PER_WAVE];
        if (it < 4) {
            int jn = (c + 8) * 256 + lane * 4;
            jn = (jn < F_IN) ? jn : 0;      // pad cols: value irrelevant (A=0), address safety only
#pragma unroll
            for (int r = 0; r < ROWS_PER_WAVE; r++)
                xn[r] = *(const float4*)(xr[r] + jn);
        }

#pragma unroll
        for (int r = 0; r < ROWS_PER_WAVE; r++) {
            float m0, s0, m1, s1, m2, s2, m3, s3;
            col_term(xv[r].x, A0.x, B0.x, C0.x, A1.x, B1.x, C1.x, A2.x, B2.x, C2.x, m0, s0);
            col_term(xv[r].y, A0.y, B0.y, C0.y, A1.y, B1.y, C1.y, A2.y, B2.y, C2.y, m1, s1);
            col_term(xv[r].z, A0.z, B0.z, C0.z, A1.z, B1.z, C1.z, A2.z, B2.z, C2.z, m2, s2);
            col_term(xv[r].w, A0.w, B0.w, C0.w, A1.w, B1.w, C1.w, A2.w, B2.w, C2.w, m3, s3);
            // no masking: pad columns contribute mx=0, s=1 by construction
            accm[r] += (m0 + m1) + (m2 + m3);
            prod[r] *= (s0 * s1) * (s2 * s3);
        }

        if (it < 4) {
#pragma unroll
            for (int r = 0; r < ROWS_PER_WAVE; r++) xv[r] = xn[r];
        }
    }

#pragma unroll
    for (int r = 0; r < ROWS_PER_WAVE; r++) {
        float part = LN2 * (accm[r] + __log2f(prod[r]));   // back to natural-log domain
#pragma unroll
        for (int off = 32; off > 0; off >>= 1)
            part += __shfl_xor(part, off, 64);
        if (lane == 0)
            atomicAdd(&out[row0 + r], part);
    }
}

extern "C" void kernel_launch(void* const* d_in, const int* in_sizes, int n_in,
                              void* d_out, int out_size, void* d_ws, size_t ws_size,
                              hipStream_t stream) {
    const float* x         = (const float*)d_in[0];
    const float* means     = (const float*)d_in[1];
    const float* stds      = (const float*)d_in[2];
    const float* w1        = (const float*)d_in[3];
    // w2..w5 (d_in[4..7]) are identity under log_softmax over a size-1 axis
    const int*   rand_idxs = (const int*)d_in[8];

    float* out = (float*)d_out;
    float* ws  = (float*)d_ws;   // needs 9 * 10240 * 4 B = 368,640 B

    // prep: SoA log2-domain constants (incl. neutral pad cols) + zero the output
    spn_prep_kernel<<<NPADCOL / 256, 256, 0, stream>>>(means, stds, w1, rand_idxs, ws, out);

    // main: 256 row-blocks (16 rows) x 8 column-groups = 2048 blocks
    spn_main_kernel<<<256 * CGROUPS, 256, 0, stream>>>(x, ws, out);
}

// Round 3
// 245.595 us; speedup vs baseline: 1.7551x; 1.0806x over previous
//
#include <hip/hip_runtime.h>
#include <math.h>

#define F_IN 10000
#define NROWS 4096
#define NPADCOL 10240          // padded to 8 stripes of 1280 cols
#define CGROUPS 8
#define ROWS_PER_WAVE 4        // 4 rows/wave x 4 waves = 16 rows/block

#define LOG2E      1.44269504088896340736f
#define SQRT_LOG2E 1.20112240878645f   // sqrt(log2(e))
#define LN2        0.69314718055994530942f

// ws layout: SoA, 9 arrays of NPADCOL floats, column-ordered (coalesced across lanes):
//   [0..2]*NPADCOL : A_m = sqrt(log2e)/(std*sqrt(2))
//   [3..5]*NPADCOL : B_m = -mean*A_m
//   [6..8]*NPADCOL : C_m = (logw_m - log(std) - 0.5*log(2pi)) * log2e
// log2-domain: v_m = C_m - (A_m*x + B_m)^2 is the log2-prob of component m.
// Pad columns j in [10000,10240): A=B=0, C=(0,-1e30,-1e30) -> mx=0, s=1 (neutral).
__global__ void spn_prep_kernel(const float* __restrict__ means,
                                const float* __restrict__ stds,
                                const float* __restrict__ w1,
                                const int* __restrict__ rand_idxs,
                                float* __restrict__ ws,
                                float* __restrict__ out) {
    int f = blockIdx.x * blockDim.x + threadIdx.x;   // 0..10239 (40 blocks x 256)
    if (f < NROWS) out[f] = 0.0f;                    // zero output for atomic accumulation
    if (f >= NPADCOL) return;

    if (f >= F_IN) {
        // rand_idxs is a permutation of 0..9999, so columns >=10000 are exactly the pads
#pragma unroll
        for (int m = 0; m < 3; m++) {
            ws[(0 + m) * NPADCOL + f] = 0.0f;                       // A
            ws[(3 + m) * NPADCOL + f] = 0.0f;                       // B
            ws[(6 + m) * NPADCOL + f] = (m == 0) ? 0.0f : -1e30f;   // C
        }
        return;
    }

    int j = rand_idxs[f];                   // column of x this feature reads

    float wa = w1[f * 3 + 0];
    float wb = w1[f * 3 + 1];
    float wc = w1[f * 3 + 2];
    float wm = fmaxf(fmaxf(wa, wb), wc);
    float lse = wm + __logf(__expf(wa - wm) + __expf(wb - wm) + __expf(wc - wm));

    const float INV_SQRT2 = 0.70710678118654752440f;
    const float HALF_LOG_2PI = 0.91893853320467274178f;

#pragma unroll
    for (int m = 0; m < 3; m++) {
        float w  = w1[f * 3 + m] - lse;                 // log_softmax (natural log)
        float sd = stds[f * 3 + m];
        float mu = means[f * 3 + m];
        float a  = (INV_SQRT2 * SQRT_LOG2E) / sd;       // sqrt(log2e) folded into scale
        float b  = -mu * a;
        float c  = (w - __logf(sd) - HALF_LOG_2PI) * LOG2E;
        ws[(0 + m) * NPADCOL + j] = a;
        ws[(3 + m) * NPADCOL + j] = b;
        ws[(6 + m) * NPADCOL + j] = c;
    }
}

// per-column mixture term in log2 domain: mx = max of 3 log2-probs, s = sum 2^(v-mx), s in [1,3]
// __builtin_amdgcn_exp2f = bare v_exp_f32 (plain exp2f routes through OCML and is ~8 instrs — R2 regression)
__device__ __forceinline__ void col_term(float xv,
                                         float a0, float b0, float c0,
                                         float a1, float b1, float c1,
                                         float a2, float b2, float c2,
                                         float& mx_out, float& s_out) {
    float u0 = fmaf(xv, a0, b0);
    float u1 = fmaf(xv, a1, b1);
    float u2 = fmaf(xv, a2, b2);
    float v0 = fmaf(-u0, u0, c0);           // C - (z^2/2)*log2e
    float v1 = fmaf(-u1, u1, c1);
    float v2 = fmaf(-u2, u2, c2);
    float mx = fmaxf(fmaxf(v0, v1), v2);    // -> v_max3
    float me = __builtin_amdgcn_fmed3f(v0, v1, v2);
    float mn = fminf(fminf(v0, v1), v2);    // -> v_min3
    float s  = 1.0f + __builtin_amdgcn_exp2f(me - mx) + __builtin_amdgcn_exp2f(mn - mx);
    mx_out = mx;
    s_out  = s;
}

// 256 row-blocks (16 rows) x 8 column-stripes = 2048 blocks; 4 waves/block
// blockIdx = rb*8 + cg -> default XCD round-robin puts all of stripe cg on XCD cg:
// its 46 KB ws slice stays hot in that XCD's L2; x streaming = 8 disjoint sequential stripes.
__global__ __launch_bounds__(256) void spn_main_kernel(const float* __restrict__ x,
                                                       const float* __restrict__ ws,
                                                       float* __restrict__ out) {
    const int wave = threadIdx.x >> 6;
    const int lane = threadIdx.x & 63;
    const int rb   = blockIdx.x >> 3;       // row-block: 0..255
    const int cg   = blockIdx.x & 7;        // column-stripe: 0..7, cols [cg*1280, cg*1280+1280)
    const int row0 = rb * (ROWS_PER_WAVE * 4) + wave * ROWS_PER_WAVE;

    float accm[ROWS_PER_WAVE];              // sum of per-col maxes (log2 domain)
    float prod[ROWS_PER_WAVE];              // product of s factors (<= 3^20, safe in fp32)
#pragma unroll
    for (int r = 0; r < ROWS_PER_WAVE; r++) { accm[r] = 0.0f; prod[r] = 1.0f; }

    const float* xr[ROWS_PER_WAVE];
#pragma unroll
    for (int r = 0; r < ROWS_PER_WAVE; r++) xr[r] = x + (size_t)(row0 + r) * F_IN;

    const int jbase = cg * 1280 + lane * 4; // stripe-contiguous: j = jbase + it*256

    // prologue: it0 x loads (max col = 8960+252 < 10000, always valid)
    float4 xv[ROWS_PER_WAVE];
#pragma unroll
    for (int r = 0; r < ROWS_PER_WAVE; r++)
        xv[r] = *(const float4*)(xr[r] + jbase);

#pragma unroll
    for (int it = 0; it < 5; ++it) {
        const int q = (jbase >> 2) + it * 64;      // 4-col group index, < 2560 (padded arrays)

        // current chunk params (SoA, coalesced: lanes read consecutive float4s; XCD-L2-hot)
        const float4 A0 = ((const float4*)(ws + 0 * NPADCOL))[q];
        const float4 A1 = ((const float4*)(ws + 1 * NPADCOL))[q];
        const float4 A2 = ((const float4*)(ws + 2 * NPADCOL))[q];
        const float4 B0 = ((const float4*)(ws + 3 * NPADCOL))[q];
        const float4 B1 = ((const float4*)(ws + 4 * NPADCOL))[q];
        const float4 B2 = ((const float4*)(ws + 5 * NPADCOL))[q];
        const float4 C0 = ((const float4*)(ws + 6 * NPADCOL))[q];
        const float4 C1 = ((const float4*)(ws + 7 * NPADCOL))[q];
        const float4 C2 = ((const float4*)(ws + 8 * NPADCOL))[q];

        // software-pipeline: issue next chunk's x loads (HBM) before computing
        float4 xn[ROWS_PER_WAVE];
        if (it < 4) {
            int jn = jbase + (it + 1) * 256;
            jn = (jn < F_IN) ? jn : 0;      // pad cols: value irrelevant (A=0), address safety only
#pragma unroll
            for (int r = 0; r < ROWS_PER_WAVE; r++)
                xn[r] = *(const float4*)(xr[r] + jn);
        }

#pragma unroll
        for (int r = 0; r < ROWS_PER_WAVE; r++) {
            float m0, s0, m1, s1, m2, s2, m3, s3;
            col_term(xv[r].x, A0.x, B0.x, C0.x, A1.x, B1.x, C1.x, A2.x, B2.x, C2.x, m0, s0);
            col_term(xv[r].y, A0.y, B0.y, C0.y, A1.y, B1.y, C1.y, A2.y, B2.y, C2.y, m1, s1);
            col_term(xv[r].z, A0.z, B0.z, C0.z, A1.z, B1.z, C1.z, A2.z, B2.z, C2.z, m2, s2);
            col_term(xv[r].w, A0.w, B0.w, C0.w, A1.w, B1.w, C1.w, A2.w, B2.w, C2.w, m3, s3);
            // no masking: pad columns contribute mx=0, s=1 by construction
            accm[r] += (m0 + m1) + (m2 + m3);
            prod[r] *= (s0 * s1) * (s2 * s3);
        }

        if (it < 4) {
#pragma unroll
            for (int r = 0; r < ROWS_PER_WAVE; r++) xv[r] = xn[r];
        }
    }

#pragma unroll
    for (int r = 0; r < ROWS_PER_WAVE; r++) {
        float part = LN2 * (accm[r] + __log2f(prod[r]));   // back to natural-log domain
#pragma unroll
        for (int off = 32; off > 0; off >>= 1)
            part += __shfl_xor(part, off, 64);
        if (lane == 0)
            atomicAdd(&out[row0 + r], part);
    }
}

extern "C" void kernel_launch(void* const* d_in, const int* in_sizes, int n_in,
                              void* d_out, int out_size, void* d_ws, size_t ws_size,
                              hipStream_t stream) {
    const float* x         = (const float*)d_in[0];
    const float* means     = (const float*)d_in[1];
    const float* stds      = (const float*)d_in[2];
    const float* w1        = (const float*)d_in[3];
    // w2..w5 (d_in[4..7]) are identity under log_softmax over a size-1 axis
    const int*   rand_idxs = (const int*)d_in[8];

    float* out = (float*)d_out;
    float* ws  = (float*)d_ws;   // needs 9 * 10240 * 4 B = 368,640 B

    // prep: SoA log2-domain constants (incl. neutral pad cols) + zero the output
    spn_prep_kernel<<<NPADCOL / 256, 256, 0, stream>>>(means, stds, w1, rand_idxs, ws, out);

    // main: 256 row-blocks (16 rows) x 8 column-stripes = 2048 blocks
    spn_main_kernel<<<256 * CGROUPS, 256, 0, stream>>>(x, ws, out);
}